// Round 5
// baseline (1292.344 us; speedup 1.0000x reference)
//
#include <hip/hip_runtime.h>

#define THREADS 256
#define FGRID   1024   // 4 blocks/CU x 256 CU; residency guaranteed by launch_bounds(256,4)
                       // (m69: 16 waves/CU needs VGPR<=128; LDS 16.9KB*4=67.6KB<160KB)

typedef float v4f __attribute__((ext_vector_type(4)));

// ---------------- device-scope grid barrier (persistent grid) ----------------
// bar[0]=arrive counter (zeroed by memset + reset by last arriver)
// bar[1]=generation     (zeroed by memset each invocation)
__device__ __forceinline__ void gbar(int* bar, int nb, int gen) {
    __threadfence();                 // publish this thread's global writes (device scope)
    __syncthreads();
    if (threadIdx.x == 0) {
        int old = __hip_atomic_fetch_add(&bar[0], 1, __ATOMIC_ACQ_REL,
                                         __HIP_MEMORY_SCOPE_AGENT);
        if (old == nb - 1) {
            __hip_atomic_store(&bar[0], 0, __ATOMIC_RELAXED, __HIP_MEMORY_SCOPE_AGENT);
            __hip_atomic_fetch_add(&bar[1], 1, __ATOMIC_RELEASE, __HIP_MEMORY_SCOPE_AGENT);
        } else {
            while (__hip_atomic_load(&bar[1], __ATOMIC_ACQUIRE,
                                     __HIP_MEMORY_SCOPE_AGENT) < gen)
                __builtin_amdgcn_s_sleep(8);
        }
    }
    __syncthreads();
}

// ---------------- fused pipeline: hist -> scan -> scatter -> agg ----------------
// payload row (12 floats, 48B, 16B-aligned): [s,u0,u1,u2 | Q00,Q01,Q02,Q11 | Q12,Q22,src,0]

#define ACC_STRIDE 15   // 14 used +1 pad to break LDS bank conflicts

__global__ __launch_bounds__(THREADS, 4)
void k_fused(const float* __restrict__ node,
             const int*   __restrict__ eidx,
             const float* __restrict__ sh0,
             const float* __restrict__ sh1,
             const float* __restrict__ sh2,
             const float* __restrict__ W,
             float*       __restrict__ out,
             int* bar, int* cnt, int* rowptr, int* bsum, int* ke,
             float* __restrict__ pay,
             int N, int E) {
    __shared__ float sW[384];
    __shared__ float sAcc[32 * 8 * ACC_STRIDE];   // reused as int[] scratch for scans

    const int NB  = gridDim.x;
    const int tid = threadIdx.x;

    for (int t = tid; t < 384; t += THREADS) sW[t] = W[t];

    constexpr float IS3  = 0.57735026918962576f;
    constexpr float IS6  = 0.40824829046386302f;
    constexpr float IS10 = 0.31622776601683794f;
    constexpr float IS30 = 0.18257418583505536f;

    // ---- P1: histogram + per-edge rank (cnt was zeroed by host memset) ----
    for (int e = blockIdx.x * THREADS + tid; e < E; e += NB * THREADS)
        ke[e] = atomicAdd(&cnt[eidx[E + e]], 1);

    gbar(bar, NB, 1);

    // ---- P2a: per-chunk partial sums (chunk = 1024 counters per block) ----
    {
        int* lds = (int*)sAcc;
        int base = blockIdx.x * 1024 + tid * 4;
        int s = 0;
        #pragma unroll
        for (int k = 0; k < 4; ++k) { int i = base + k; if (i < N) s += cnt[i]; }
        lds[tid] = s; __syncthreads();
        for (int off = THREADS / 2; off > 0; off >>= 1) {
            if (tid < off) lds[tid] += lds[tid + off];
            __syncthreads();
        }
        if (tid == 0) bsum[blockIdx.x] = lds[0];
    }

    gbar(bar, NB, 2);

    // ---- P2b: block 0 exclusive-scans bsum[FGRID] (4 per thread) ----
    if (blockIdx.x == 0) {
        int* lds = (int*)sAcc;
        int v[4]; int loc = 0;
        #pragma unroll
        for (int k = 0; k < 4; ++k) { v[k] = bsum[tid * 4 + k]; loc += v[k]; }
        lds[tid] = loc; __syncthreads();
        for (int off = 1; off < THREADS; off <<= 1) {
            int x = (tid >= off) ? lds[tid - off] : 0;
            __syncthreads();
            lds[tid] += x;
            __syncthreads();
        }
        int p = lds[tid] - loc;          // exclusive prefix of this thread's group
        #pragma unroll
        for (int k = 0; k < 4; ++k) { bsum[tid * 4 + k] = p; p += v[k]; }
    }

    gbar(bar, NB, 3);

    // ---- P2c: finalize rowptr for this chunk ----
    {
        int* lds = (int*)sAcc;
        int base = blockIdx.x * 1024 + tid * 4;
        int v[4]; int local = 0;
        #pragma unroll
        for (int k = 0; k < 4; ++k) {
            int i = base + k;
            v[k] = (i < N) ? cnt[i] : 0;
            local += v[k];
        }
        lds[tid] = local; __syncthreads();
        for (int off = 1; off < THREADS; off <<= 1) {
            int x = (tid >= off) ? lds[tid - off] : 0;
            __syncthreads();
            lds[tid] += x;
            __syncthreads();
        }
        int p = lds[tid] - local + bsum[blockIdx.x];
        #pragma unroll
        for (int k = 0; k < 4; ++k) {
            int i = base + k;
            if (i < N) { rowptr[i] = p; p += v[k]; }
        }
        if (blockIdx.x == 0 && tid == 0) rowptr[N] = E;
    }

    gbar(bar, NB, 4);

    // ---- P3: scatter 48B payload into CSR order (rank-based, no atomics) ----
    for (int e = blockIdx.x * THREADS + tid; e < E; e += NB * THREADS) {
        const int src = eidx[e];
        const int tgt = eidx[E + e];
        const int pos = rowptr[tgt] + ke[e];

        const float s  = __builtin_nontemporal_load(&sh0[e]);
        const float u0 = __builtin_nontemporal_load(&sh1[3*e+0]);
        const float u1 = __builtin_nontemporal_load(&sh1[3*e+1]);
        const float u2 = __builtin_nontemporal_load(&sh1[3*e+2]);
        const float q0 = __builtin_nontemporal_load(&sh2[5*e+0]);
        const float q1 = __builtin_nontemporal_load(&sh2[5*e+1]);
        const float q2 = __builtin_nontemporal_load(&sh2[5*e+2]);
        const float q3 = __builtin_nontemporal_load(&sh2[5*e+3]);
        const float q4 = __builtin_nontemporal_load(&sh2[5*e+4]);

        const float Q00 = -q2*IS30 - q4*IS10;
        const float Q01 =  q1*IS10;
        const float Q02 =  q0*IS10;
        const float Q11 =  2.0f*q2*IS30;
        const float Q12 =  q3*IS10;
        const float Q22 = -q2*IS30 + q4*IS10;

        float4* pr = (float4*)(pay + (size_t)pos * 12);
        pr[0] = make_float4(s, u0, u1, u2);
        pr[1] = make_float4(Q00, Q01, Q02, Q11);
        pr[2] = make_float4(Q12, Q22, __int_as_float(src), 0.f);
    }

    gbar(bar, NB, 5);

    // ---- P4: aggregation, one wave per node (64 lanes = 8 edges x 8 channels) ----
    const int lane  = tid & 63;
    const int wv    = tid >> 6;
    const int i     = lane & 7;
    const int jslot = lane >> 3;

    for (int nb0 = blockIdx.x * 32; nb0 < N; nb0 += NB * 32) {
        for (int t = 0; t < 8; ++t) {
            const int n = nb0 + wv * 8 + t;   // wave-uniform

            float a[14];
            #pragma unroll
            for (int k = 0; k < 14; ++k) a[k] = 0.f;

            if (n < N) {
                const int jbeg = rowptr[n];
                const int jend = rowptr[n + 1];

                if (jbeg < jend) {
                    // prologue: group 0 payload + node vec
                    int j  = jbeg + jslot;
                    int jc = (j < jend) ? j : (jend - 1);
                    float mcur = (j < jend) ? 1.f : 0.f;
                    const v4f* p = (const v4f*)(pay + (size_t)jc * 12);
                    v4f c0 = p[0], c1 = p[1], c2 = p[2];
                    int src = __float_as_int(c2[2]);
                    const float* nr = node + (size_t)src * 32;
                    v4f nf;
                    nf[0] = nr[i];
                    nf[1] = nr[8 + 3*i + 0];
                    nf[2] = nr[8 + 3*i + 1];
                    nf[3] = nr[8 + 3*i + 2];

                    for (int g0 = jbeg; g0 < jend; g0 += 8) {
                        const int gn = g0 + 8;
                        const bool more = gn < jend;   // wave-uniform
                        v4f d0, d1, d2; float mnext = 0.f;
                        if (more) {
                            int jn  = gn + jslot;
                            int jnc = (jn < jend) ? jn : (jend - 1);
                            mnext = (jn < jend) ? 1.f : 0.f;
                            const v4f* pn = (const v4f*)(pay + (size_t)jnc * 12);
                            d0 = pn[0]; d1 = pn[1]; d2 = pn[2];
                        }

                        const float f0 = nf[0] * mcur;
                        const float x  = nf[1] * mcur;
                        const float y  = nf[2] * mcur;
                        const float z  = nf[3] * mcur;
                        const float s   = c0[0], u0 = c0[1], u1 = c0[2], u2 = c0[3];
                        const float Q00 = c1[0], Q01 = c1[1], Q02 = c1[2], Q11 = c1[3];
                        const float Q12 = c2[0], Q22 = c2[1];

                        a[0]  += s * f0;
                        a[1]  += u0*x + u1*y + u2*z;
                        a[2]  += s * x;
                        a[3]  += s * y;
                        a[4]  += s * z;
                        a[5]  += f0 * u0;
                        a[6]  += f0 * u1;
                        a[7]  += f0 * u2;
                        a[8]  += u1*z - u2*y;
                        a[9]  += u2*x - u0*z;
                        a[10] += u0*y - u1*x;
                        a[11] += Q00*x + Q01*y + Q02*z;
                        a[12] += Q01*x + Q11*y + Q12*z;
                        a[13] += Q02*x + Q12*y + Q22*z;

                        if (more) {
                            int srcn = __float_as_int(d2[2]);
                            const float* nrn = node + (size_t)srcn * 32;
                            nf[0] = nrn[i];
                            nf[1] = nrn[8 + 3*i + 0];
                            nf[2] = nrn[8 + 3*i + 1];
                            nf[3] = nrn[8 + 3*i + 2];
                            c0 = d0; c1 = d1; c2 = d2; mcur = mnext;
                        }
                    }
                }
            }

            // reduce across the 8 edge slots (lane bits 3..5)
            #pragma unroll
            for (int k = 0; k < 14; ++k) {
                float v = a[k];
                v += __shfl_xor(v, 8);
                v += __shfl_xor(v, 16);
                v += __shfl_xor(v, 32);
                a[k] = v;
            }

            if (n < N && jslot == 0) {
                #pragma unroll
                for (int k = 1; k < 8; ++k) a[k] *= IS3;
                #pragma unroll
                for (int k = 8; k < 11; ++k) a[k] *= IS6;
                float* myAcc = &sAcc[((wv * 8 + t) * 8 + i) * ACC_STRIDE];
                #pragma unroll
                for (int k = 0; k < 14; ++k) myAcc[k] = a[k];
            }
        }
        __syncthreads();

        // per-node postmix, 8 threads per node
        {
            const int nodeSlot = tid >> 3;
            const int o        = tid & 7;
            const int n        = nb0 + nodeSlot;
            if (n < N) {
                float o0 = 0.f, ox = 0.f, oy = 0.f, oz = 0.f;
                #pragma unroll
                for (int ii = 0; ii < 8; ++ii) {
                    const float* A = &sAcc[(nodeSlot * 8 + ii) * ACC_STRIDE];
                    const float w0 = sW[  0 + ii*8 + o];
                    const float w1 = sW[ 64 + ii*8 + o];
                    const float w2 = sW[128 + ii*8 + o];
                    const float w3 = sW[192 + ii*8 + o];
                    const float w4 = sW[256 + ii*8 + o];
                    const float w5 = sW[320 + ii*8 + o];
                    o0 += w0*A[0]  + w3*A[1];
                    ox += w1*A[2]  + w2*A[5] + w4*A[8]  + w5*A[11];
                    oy += w1*A[3]  + w2*A[6] + w4*A[9]  + w5*A[12];
                    oz += w1*A[4]  + w2*A[7] + w4*A[10] + w5*A[13];
                }
                float* orow = out + (size_t)n * 32;
                orow[o]         = o0;
                orow[8 + 3*o+0] = ox;
                orow[8 + 3*o+1] = oy;
                orow[8 + 3*o+2] = oz;
            }
        }
        __syncthreads();   // sAcc reused next round
    }
}

// ---------------- fallback: atomic kernel (ws-free) ----------------

__global__ __launch_bounds__(THREADS) void msg_kernel_atomic(
    const float* __restrict__ node,
    const int*   __restrict__ eidx,
    const float* __restrict__ sh0,
    const float* __restrict__ sh1,
    const float* __restrict__ sh2,
    const float* __restrict__ W,
    float*       __restrict__ out,
    int E)
{
    __shared__ float sW[384];
    for (int t = threadIdx.x; t < 384; t += THREADS) sW[t] = W[t];
    __syncthreads();

    int e = blockIdx.x * THREADS + threadIdx.x;
    if (e >= E) return;

    constexpr float IS3  = 0.57735026918962576f;
    constexpr float IS6  = 0.40824829046386302f;
    constexpr float IS10 = 0.31622776601683794f;
    constexpr float IS30 = 0.18257418583505536f;

    const int src = eidx[e];
    const int tgt = eidx[E + e];

    const float s  = sh0[e];
    const float u0 = sh1[3*e+0], u1 = sh1[3*e+1], u2 = sh1[3*e+2];
    const float q0 = sh2[5*e+0], q1 = sh2[5*e+1], q2 = sh2[5*e+2],
                q3 = sh2[5*e+3], q4 = sh2[5*e+4];

    const float Q00 = -q2*IS30 - q4*IS10;
    const float Q01 =  q1*IS10;
    const float Q02 =  q0*IS10;
    const float Q11 =  2.0f*q2*IS30;
    const float Q12 =  q3*IS10;
    const float Q22 = -q2*IS30 + q4*IS10;

    float f[32];
    {
        const float4* nr = (const float4*)(node + (size_t)src * 32);
        #pragma unroll
        for (int i = 0; i < 8; ++i) {
            float4 v = nr[i];
            f[4*i+0]=v.x; f[4*i+1]=v.y; f[4*i+2]=v.z; f[4*i+3]=v.w;
        }
    }

    float msg[32];
    #pragma unroll
    for (int j = 0; j < 32; ++j) msg[j] = 0.0f;

    const float s13 = s * IS3;

    #pragma unroll
    for (int i = 0; i < 8; ++i) {
        const float f0i = f[i];
        const float x = f[8+3*i+0], y = f[8+3*i+1], z = f[8+3*i+2];
        const float c0  = s * f0i;
        const float c3  = IS3 * (u0*x + u1*y + u2*z);
        const float p2  = IS3 * f0i;
        const float c1x = s13*x, c1y = s13*y, c1z = s13*z;
        const float c2x = p2*u0, c2y = p2*u1, c2z = p2*u2;
        const float c4x = IS6*(u1*z - u2*y);
        const float c4y = IS6*(u2*x - u0*z);
        const float c4z = IS6*(u0*y - u1*x);
        const float c5x = Q00*x + Q01*y + Q02*z;
        const float c5y = Q01*x + Q11*y + Q12*z;
        const float c5z = Q02*x + Q12*y + Q22*z;

        float wr[6][8];
        #pragma unroll
        for (int c = 0; c < 6; ++c) {
            float4 aa = *(const float4*)&sW[c*64 + i*8 + 0];
            float4 bb = *(const float4*)&sW[c*64 + i*8 + 4];
            wr[c][0]=aa.x; wr[c][1]=aa.y; wr[c][2]=aa.z; wr[c][3]=aa.w;
            wr[c][4]=bb.x; wr[c][5]=bb.y; wr[c][6]=bb.z; wr[c][7]=bb.w;
        }

        #pragma unroll
        for (int o = 0; o < 8; ++o) {
            msg[o] += wr[0][o]*c0 + wr[3][o]*c3;
            msg[8+3*o+0] += wr[1][o]*c1x + wr[2][o]*c2x + wr[4][o]*c4x + wr[5][o]*c5x;
            msg[8+3*o+1] += wr[1][o]*c1y + wr[2][o]*c2y + wr[4][o]*c4y + wr[5][o]*c5y;
            msg[8+3*o+2] += wr[1][o]*c1z + wr[2][o]*c2z + wr[4][o]*c4z + wr[5][o]*c5z;
        }
    }

    float* orow = out + (size_t)tgt * 32;
    #pragma unroll
    for (int j = 0; j < 32; ++j) unsafeAtomicAdd(orow + j, msg[j]);
}

// ---------------- host ----------------

extern "C" void kernel_launch(void* const* d_in, const int* in_sizes, int n_in,
                              void* d_out, int out_size, void* d_ws, size_t ws_size,
                              hipStream_t stream) {
    const float* node = (const float*)d_in[0];
    const int*   eidx = (const int*)d_in[1];
    const float* sh0  = (const float*)d_in[2];
    const float* sh1  = (const float*)d_in[3];
    const float* sh2  = (const float*)d_in[4];
    const float* W    = (const float*)d_in[5];
    float* out = (float*)d_out;

    const int E = in_sizes[2];          // sh0 has E elements
    const int N = in_sizes[0] / 32;     // node_irreps is [N, 32]

    // ws layout (ints): bar[2] | cnt[N] | rowptr[N+1] | bsum[FGRID] | ke[E] | (16-align) pay[12E]
    size_t off = 0;
    size_t off_bar    = off; off += 2;
    size_t off_cnt    = off; off += (size_t)N;
    size_t off_rowptr = off; off += (size_t)N + 1;
    size_t off_bsum   = off; off += FGRID;
    size_t off_ke     = off; off += (size_t)E;
    off = (off + 15) & ~(size_t)15;                    // 64B-align payload
    size_t off_pay    = off; off += (size_t)E * 12;
    size_t need = off * sizeof(float);

    // scan coverage: chunk = 1024 counters/block -> N must fit FGRID*1024
    if (ws_size >= need && N <= FGRID * 1024) {
        int* wsI    = (int*)d_ws;
        int* bar    = wsI + off_bar;
        int* cnt    = wsI + off_cnt;
        int* rowptr = wsI + off_rowptr;
        int* bsum   = wsI + off_bsum;
        int* ke     = wsI + off_ke;
        float* pay  = (float*)d_ws + off_pay;

        // zero bar+cnt in one contiguous memset (they are adjacent by layout)
        hipMemsetAsync(bar, 0, (size_t)(2 + N) * sizeof(int), stream);

        k_fused<<<FGRID, THREADS, 0, stream>>>(node, eidx, sh0, sh1, sh2, W, out,
                                               bar, cnt, rowptr, bsum, ke, pay,
                                               N, E);
    } else {
        hipMemsetAsync(d_out, 0, (size_t)out_size * sizeof(float), stream);
        msg_kernel_atomic<<<(E + THREADS - 1) / THREADS, THREADS, 0, stream>>>(
            node, eidx, sh0, sh1, sh2, W, out, E);
    }
}

// Round 7
// 576.769 us; speedup vs baseline: 2.2407x; 2.2407x over previous
//
#include <hip/hip_runtime.h>

#define THREADS 256

typedef float v4f __attribute__((ext_vector_type(4)));

// ---------------- CSR build ----------------

// counts + per-target rank (atomic return value) -> scatter needs no atomics
__global__ __launch_bounds__(THREADS) void k_hist2(const int* __restrict__ tgt,
                                                   int* __restrict__ cnt,
                                                   int* __restrict__ ke, int E) {
    int e = blockIdx.x * THREADS + threadIdx.x;
    if (e < E) ke[e] = atomicAdd(&cnt[tgt[e]], 1);
}

// counts only (tier without ke array)
__global__ __launch_bounds__(THREADS) void k_hist(const int* __restrict__ tgt,
                                                  int* __restrict__ cnt, int E) {
    int e = blockIdx.x * THREADS + threadIdx.x;
    if (e < E) atomicAdd(&cnt[tgt[e]], 1);
}

// ---------------- single-block exclusive scan (replaces 3-kernel scan chain) ----
// 1024 threads x ~98 counters each; ~1.2MB L2/L3 traffic total. Writes rowptr
// AND cnt[i]=prefix (running cursor for the atomic-tier scatter).

__global__ __launch_bounds__(1024) void k_scan1(int* __restrict__ cnt,
                                                int* __restrict__ rowptr,
                                                int N, int E) {
    __shared__ int lds[1024];
    const int t = threadIdx.x;
    const int chunk = (N + 1023) >> 10;
    const int lo = t * chunk;
    const int hi = (lo + chunk < N) ? lo + chunk : N;

    int s = 0;
    for (int i = lo; i < hi; ++i) s += cnt[i];
    lds[t] = s; __syncthreads();
    for (int off = 1; off < 1024; off <<= 1) {
        int x = (t >= off) ? lds[t - off] : 0;
        __syncthreads();
        lds[t] += x;
        __syncthreads();
    }
    int p = lds[t] - s;                 // exclusive prefix of this thread's chunk
    for (int i = lo; i < hi; ++i) {
        int c = cnt[i];
        rowptr[i] = p;
        cnt[i] = p;                     // cursor copy for atomic-tier scatter
        p += c;
    }
    if (t == 0) rowptr[N] = E;
}

// ---------------- scatter payload into CSR order (full 64B rows) ----------------
// payload row (16 floats, 64B): [s,u0,u1,u2 | Q00,Q01,Q02,Q11 | Q12,Q22,src,0 | 0,0,0,0]
// R0/R5 lesson: rows MUST be full 64B-aligned lines -- random 64B full-line writes pay
// no fill (WRITE_SIZE == payload bytes); 48B rows straddle sectors (R5: 227MB writes).
// Rank-based (ke) -> no atomics here (R3: atomic cursor added ~48MB RMW traffic).
// Plain stores so L2 merges the 4x16B into one line writeback (nt stores bypass: 2.4x).

__global__ __launch_bounds__(THREADS) void k_scatter5(const int* __restrict__ eidx,
                                                      const int* __restrict__ ke,    // null => atomic
                                                      const int* __restrict__ rowptr,
                                                      int* __restrict__ cursor,
                                                      const float* __restrict__ sh0,
                                                      const float* __restrict__ sh1,
                                                      const float* __restrict__ sh2,
                                                      float* __restrict__ pay,
                                                      int E) {
    int e = blockIdx.x * THREADS + threadIdx.x;
    if (e >= E) return;

    constexpr float IS10 = 0.31622776601683794f;
    constexpr float IS30 = 0.18257418583505536f;

    const int src = eidx[e];
    const int tgt = eidx[E + e];
    int pos;
    if (ke) pos = rowptr[tgt] + ke[e];
    else    pos = atomicAdd(&cursor[tgt], 1);

    // sequential input streams; nt so 58MB of sh doesn't evict hot data
    const float s  = __builtin_nontemporal_load(&sh0[e]);
    const float u0 = __builtin_nontemporal_load(&sh1[3*e+0]);
    const float u1 = __builtin_nontemporal_load(&sh1[3*e+1]);
    const float u2 = __builtin_nontemporal_load(&sh1[3*e+2]);
    const float q0 = __builtin_nontemporal_load(&sh2[5*e+0]);
    const float q1 = __builtin_nontemporal_load(&sh2[5*e+1]);
    const float q2 = __builtin_nontemporal_load(&sh2[5*e+2]);
    const float q3 = __builtin_nontemporal_load(&sh2[5*e+3]);
    const float q4 = __builtin_nontemporal_load(&sh2[5*e+4]);

    const float Q00 = -q2*IS30 - q4*IS10;
    const float Q01 =  q1*IS10;
    const float Q02 =  q0*IS10;
    const float Q11 =  2.0f*q2*IS30;
    const float Q12 =  q3*IS10;
    const float Q22 = -q2*IS30 + q4*IS10;

    float4* pr = (float4*)(pay + (size_t)pos * 16);
    pr[0] = make_float4(s, u0, u1, u2);
    pr[1] = make_float4(Q00, Q01, Q02, Q11);
    pr[2] = make_float4(Q12, Q22, __int_as_float(src), 0.f);
    pr[3] = make_float4(0.f, 0.f, 0.f, 0.f);   // full 64B line, one touch
}

// ---------------- aggregation: one WAVE per node, 64 lanes = 8 edges x 8 channels ----
// - zero divergence: loop bounds wave-uniform; tail masked by scaling node vec
//   (all 14 accumulator terms are linear in f0/x/y/z)
// - payload read with PLAIN loads: just written, 102MB < 256MB L3 -> should be
//   L3-resident (nt loads in R0-R3 bypassed allocation -> full HBM re-fetch)
// - per group-iteration: 8 payload rows = 512B contiguous; 8 node lines in flight
// - 1-deep pipeline: group g+1 payload + node vecs issued while computing g
// - end of node: reduce a[14] across jslot lanes via shfl_xor(8,16,32)

#define ACC_STRIDE 15   // 14 used +1 pad to break LDS bank conflicts

__global__ __launch_bounds__(THREADS) void k_agg8(const float* __restrict__ node,   // [N][32]
                                                  const int*   __restrict__ rowptr,
                                                  const float* __restrict__ pay,
                                                  const float* __restrict__ W,
                                                  float*       __restrict__ out,
                                                  int N) {
    __shared__ float sW[384];
    __shared__ float sAcc[32 * 8 * ACC_STRIDE];
    for (int t = threadIdx.x; t < 384; t += THREADS) sW[t] = W[t];
    __syncthreads();

    constexpr float IS3 = 0.57735026918962576f;
    constexpr float IS6 = 0.40824829046386302f;

    const int lane  = threadIdx.x & 63;
    const int wv    = threadIdx.x >> 6;    // wave 0..3
    const int i     = lane & 7;            // channel
    const int jslot = lane >> 3;           // edge slot 0..7

    for (int t = 0; t < 8; ++t) {
        const int n = blockIdx.x * 32 + wv * 8 + t;   // wave-uniform

        float a[14];
        #pragma unroll
        for (int k = 0; k < 14; ++k) a[k] = 0.f;

        if (n < N) {
            const int jbeg = rowptr[n];
            const int jend = rowptr[n + 1];

            if (jbeg < jend) {
                // prologue: group 0 payload + node vec
                int j  = jbeg + jslot;
                int jc = (j < jend) ? j : (jend - 1);
                float mcur = (j < jend) ? 1.f : 0.f;
                const v4f* p = (const v4f*)(pay + (size_t)jc * 16);
                v4f c0 = p[0], c1 = p[1], c2 = p[2];
                int src = __float_as_int(c2[2]);
                const float* nr = node + (size_t)src * 32;
                v4f nf;
                nf[0] = nr[i];
                nf[1] = nr[8 + 3*i + 0];
                nf[2] = nr[8 + 3*i + 1];
                nf[3] = nr[8 + 3*i + 2];

                for (int g0 = jbeg; g0 < jend; g0 += 8) {
                    const int gn = g0 + 8;
                    const bool more = gn < jend;   // wave-uniform
                    v4f d0, d1, d2; float mnext = 0.f;
                    if (more) {
                        int jn  = gn + jslot;
                        int jnc = (jn < jend) ? jn : (jend - 1);
                        mnext = (jn < jend) ? 1.f : 0.f;
                        const v4f* pn = (const v4f*)(pay + (size_t)jnc * 16);
                        d0 = pn[0]; d1 = pn[1]; d2 = pn[2];
                    }

                    const float f0 = nf[0] * mcur;
                    const float x  = nf[1] * mcur;
                    const float y  = nf[2] * mcur;
                    const float z  = nf[3] * mcur;
                    const float s   = c0[0], u0 = c0[1], u1 = c0[2], u2 = c0[3];
                    const float Q00 = c1[0], Q01 = c1[1], Q02 = c1[2], Q11 = c1[3];
                    const float Q12 = c2[0], Q22 = c2[1];

                    a[0]  += s * f0;
                    a[1]  += u0*x + u1*y + u2*z;
                    a[2]  += s * x;
                    a[3]  += s * y;
                    a[4]  += s * z;
                    a[5]  += f0 * u0;
                    a[6]  += f0 * u1;
                    a[7]  += f0 * u2;
                    a[8]  += u1*z - u2*y;
                    a[9]  += u2*x - u0*z;
                    a[10] += u0*y - u1*x;
                    a[11] += Q00*x + Q01*y + Q02*z;
                    a[12] += Q01*x + Q11*y + Q12*z;
                    a[13] += Q02*x + Q12*y + Q22*z;

                    if (more) {
                        int srcn = __float_as_int(d2[2]);
                        const float* nrn = node + (size_t)srcn * 32;
                        nf[0] = nrn[i];
                        nf[1] = nrn[8 + 3*i + 0];
                        nf[2] = nrn[8 + 3*i + 1];
                        nf[3] = nrn[8 + 3*i + 2];
                        c0 = d0; c1 = d1; c2 = d2; mcur = mnext;
                    }
                }
            }
        }

        // reduce across the 8 edge slots (lane bits 3..5); no divergence
        #pragma unroll
        for (int k = 0; k < 14; ++k) {
            float v = a[k];
            v += __shfl_xor(v, 8);
            v += __shfl_xor(v, 16);
            v += __shfl_xor(v, 32);
            a[k] = v;
        }

        if (n < N && jslot == 0) {
            #pragma unroll
            for (int k = 1; k < 8; ++k) a[k] *= IS3;
            #pragma unroll
            for (int k = 8; k < 11; ++k) a[k] *= IS6;
            float* myAcc = &sAcc[((wv * 8 + t) * 8 + i) * ACC_STRIDE];
            #pragma unroll
            for (int k = 0; k < 14; ++k) myAcc[k] = a[k];
        }
    }
    __syncthreads();

    // per-node postmix (channel-mixing weights), 8 threads per node
    {
        const int nodeSlot = threadIdx.x >> 3;
        const int o        = threadIdx.x & 7;
        const int n        = blockIdx.x * 32 + nodeSlot;
        if (n < N) {
            float o0 = 0.f, ox = 0.f, oy = 0.f, oz = 0.f;
            #pragma unroll
            for (int ii = 0; ii < 8; ++ii) {
                const float* A = &sAcc[(nodeSlot * 8 + ii) * ACC_STRIDE];
                const float w0 = sW[  0 + ii*8 + o];
                const float w1 = sW[ 64 + ii*8 + o];
                const float w2 = sW[128 + ii*8 + o];
                const float w3 = sW[192 + ii*8 + o];
                const float w4 = sW[256 + ii*8 + o];
                const float w5 = sW[320 + ii*8 + o];
                o0 += w0*A[0]  + w3*A[1];
                ox += w1*A[2]  + w2*A[5] + w4*A[8]  + w5*A[11];
                oy += w1*A[3]  + w2*A[6] + w4*A[9]  + w5*A[12];
                oz += w1*A[4]  + w2*A[7] + w4*A[10] + w5*A[13];
            }
            float* orow = out + (size_t)n * 32;
            orow[o]         = o0;
            orow[8 + 3*o+0] = ox;
            orow[8 + 3*o+1] = oy;
            orow[8 + 3*o+2] = oz;
        }
    }
}

// ---------------- fallback: atomic kernel (ws-free) ----------------

__global__ __launch_bounds__(THREADS) void msg_kernel_atomic(
    const float* __restrict__ node,
    const int*   __restrict__ eidx,
    const float* __restrict__ sh0,
    const float* __restrict__ sh1,
    const float* __restrict__ sh2,
    const float* __restrict__ W,
    float*       __restrict__ out,
    int E)
{
    __shared__ float sW[384];
    for (int t = threadIdx.x; t < 384; t += THREADS) sW[t] = W[t];
    __syncthreads();

    int e = blockIdx.x * THREADS + threadIdx.x;
    if (e >= E) return;

    constexpr float IS3  = 0.57735026918962576f;
    constexpr float IS6  = 0.40824829046386302f;
    constexpr float IS10 = 0.31622776601683794f;
    constexpr float IS30 = 0.18257418583505536f;

    const int src = eidx[e];
    const int tgt = eidx[E + e];

    const float s  = sh0[e];
    const float u0 = sh1[3*e+0], u1 = sh1[3*e+1], u2 = sh1[3*e+2];
    const float q0 = sh2[5*e+0], q1 = sh2[5*e+1], q2 = sh2[5*e+2],
                q3 = sh2[5*e+3], q4 = sh2[5*e+4];

    const float Q00 = -q2*IS30 - q4*IS10;
    const float Q01 =  q1*IS10;
    const float Q02 =  q0*IS10;
    const float Q11 =  2.0f*q2*IS30;
    const float Q12 =  q3*IS10;
    const float Q22 = -q2*IS30 + q4*IS10;

    float f[32];
    {
        const float4* nr = (const float4*)(node + (size_t)src * 32);
        #pragma unroll
        for (int i = 0; i < 8; ++i) {
            float4 v = nr[i];
            f[4*i+0]=v.x; f[4*i+1]=v.y; f[4*i+2]=v.z; f[4*i+3]=v.w;
        }
    }

    float msg[32];
    #pragma unroll
    for (int j = 0; j < 32; ++j) msg[j] = 0.0f;

    const float s13 = s * IS3;

    #pragma unroll
    for (int i = 0; i < 8; ++i) {
        const float f0i = f[i];
        const float x = f[8+3*i+0], y = f[8+3*i+1], z = f[8+3*i+2];
        const float c0  = s * f0i;
        const float c3  = IS3 * (u0*x + u1*y + u2*z);
        const float p2  = IS3 * f0i;
        const float c1x = s13*x, c1y = s13*y, c1z = s13*z;
        const float c2x = p2*u0, c2y = p2*u1, c2z = p2*u2;
        const float c4x = IS6*(u1*z - u2*y);
        const float c4y = IS6*(u2*x - u0*z);
        const float c4z = IS6*(u0*y - u1*x);
        const float c5x = Q00*x + Q01*y + Q02*z;
        const float c5y = Q01*x + Q11*y + Q12*z;
        const float c5z = Q02*x + Q12*y + Q22*z;

        float wr[6][8];
        #pragma unroll
        for (int c = 0; c < 6; ++c) {
            float4 aa = *(const float4*)&sW[c*64 + i*8 + 0];
            float4 bb = *(const float4*)&sW[c*64 + i*8 + 4];
            wr[c][0]=aa.x; wr[c][1]=aa.y; wr[c][2]=aa.z; wr[c][3]=aa.w;
            wr[c][4]=bb.x; wr[c][5]=bb.y; wr[c][6]=bb.z; wr[c][7]=bb.w;
        }

        #pragma unroll
        for (int o = 0; o < 8; ++o) {
            msg[o] += wr[0][o]*c0 + wr[3][o]*c3;
            msg[8+3*o+0] += wr[1][o]*c1x + wr[2][o]*c2x + wr[4][o]*c4x + wr[5][o]*c5x;
            msg[8+3*o+1] += wr[1][o]*c1y + wr[2][o]*c2y + wr[4][o]*c4y + wr[5][o]*c5y;
            msg[8+3*o+2] += wr[1][o]*c1z + wr[2][o]*c2z + wr[4][o]*c4z + wr[5][o]*c5z;
        }
    }

    float* orow = out + (size_t)tgt * 32;
    #pragma unroll
    for (int j = 0; j < 32; ++j) unsafeAtomicAdd(orow + j, msg[j]);
}

// ---------------- host ----------------

extern "C" void kernel_launch(void* const* d_in, const int* in_sizes, int n_in,
                              void* d_out, int out_size, void* d_ws, size_t ws_size,
                              hipStream_t stream) {
    const float* node = (const float*)d_in[0];
    const int*   eidx = (const int*)d_in[1];
    const float* sh0  = (const float*)d_in[2];
    const float* sh1  = (const float*)d_in[3];
    const float* sh2  = (const float*)d_in[4];
    const float* W    = (const float*)d_in[5];
    float* out = (float*)d_out;

    const int E = in_sizes[2];          // sh0 has E elements
    const int N = in_sizes[0] / 32;     // node_irreps is [N, 32]

    // ws layouts (words):
    //   tierA (ke):  cnt[N] | rowptr[N+1] | ke[E] | (64B align) pay[16E]
    //   tierB:       cnt[N] | rowptr[N+1] |       (64B align) pay[16E]   (atomic cursor)
    size_t base_w = (size_t)N + (size_t)(N + 1);
    size_t intA_w = base_w + (size_t)E;
    size_t payA   = (intA_w + 15) & ~(size_t)15;
    size_t payB   = (base_w + 15) & ~(size_t)15;
    size_t needA  = (payA + (size_t)E * 16) * sizeof(float);
    size_t needB  = (payB + (size_t)E * 16) * sizeof(float);

    const int gridE = (E + THREADS - 1) / THREADS;

    if (ws_size >= needB && N <= 1024 * 4096) {
        const bool useKe = (ws_size >= needA);

        int* wsI    = (int*)d_ws;
        int* cnt    = wsI;
        int* rowptr = cnt + N;
        int* ke     = useKe ? (rowptr + (N + 1)) : nullptr;
        float* pay  = (float*)d_ws + (useKe ? payA : payB);

        hipMemsetAsync(cnt, 0, (size_t)N * sizeof(int), stream);

        if (useKe)
            k_hist2<<<gridE, THREADS, 0, stream>>>(eidx + E, cnt, ke, E);
        else
            k_hist<<<gridE, THREADS, 0, stream>>>(eidx + E, cnt, E);

        k_scan1<<<1, 1024, 0, stream>>>(cnt, rowptr, N, E);

        k_scatter5<<<gridE, THREADS, 0, stream>>>(eidx, ke, rowptr, cnt,
                                                  sh0, sh1, sh2, pay, E);

        k_agg8<<<(N + 31) / 32, THREADS, 0, stream>>>(node, rowptr, pay, W, out, N);
    } else {
        hipMemsetAsync(d_out, 0, (size_t)out_size * sizeof(float), stream);
        msg_kernel_atomic<<<gridE, THREADS, 0, stream>>>(
            node, eidx, sh0, sh1, sh2, W, out, E);
    }
}

// Round 8
// 359.385 us; speedup vs baseline: 3.5960x; 1.6049x over previous
//
#include <hip/hip_runtime.h>

#define THREADS 256

typedef float v4f __attribute__((ext_vector_type(4)));

// ---------------- CSR build ----------------

// counts + per-target rank (atomic return value) -> scatter needs no atomics
__global__ __launch_bounds__(THREADS) void k_hist2(const int* __restrict__ tgt,
                                                   int* __restrict__ cnt,
                                                   int* __restrict__ ke, int E) {
    int e = blockIdx.x * THREADS + threadIdx.x;
    if (e < E) ke[e] = atomicAdd(&cnt[tgt[e]], 1);
}

// counts only (tier without ke array)
__global__ __launch_bounds__(THREADS) void k_hist(const int* __restrict__ tgt,
                                                  int* __restrict__ cnt, int E) {
    int e = blockIdx.x * THREADS + threadIdx.x;
    if (e < E) atomicAdd(&cnt[tgt[e]], 1);
}

// per-chunk partial sums (chunk = 1024 counters per block)  [R0-proven]
__global__ __launch_bounds__(THREADS) void k_scan_partial(const int* __restrict__ cnt,
                                                          int* __restrict__ bsum, int N) {
    __shared__ int lds[THREADS];
    int base = blockIdx.x * 1024 + threadIdx.x * 4;
    int s = 0;
    #pragma unroll
    for (int k = 0; k < 4; ++k) { int i = base + k; if (i < N) s += cnt[i]; }
    lds[threadIdx.x] = s; __syncthreads();
    for (int off = THREADS / 2; off > 0; off >>= 1) {
        if (threadIdx.x < off) lds[threadIdx.x] += lds[threadIdx.x + off];
        __syncthreads();
    }
    if (threadIdx.x == 0) bsum[blockIdx.x] = lds[0];
}

// finalize: every block redundantly scans bsum[NB<=256] in LDS (trivial), then does
// R0's per-chunk exclusive scan. Merges R0's scan_bsum+scan_final -> one node.
// Also writes cnt[i]=prefix (running cursor for the atomic-tier scatter).
__global__ __launch_bounds__(THREADS) void k_scan_final2(int* __restrict__ cnt,
                                                         const int* __restrict__ bsum,
                                                         int* __restrict__ rowptr,
                                                         int N, int E, int NB) {
    __shared__ int lbs[THREADS];
    __shared__ int lds[THREADS];
    const int t = threadIdx.x;

    // block-scan bsum (inclusive) -> chunk-prefix for this block
    lbs[t] = (t < NB) ? bsum[t] : 0;
    __syncthreads();
    for (int off = 1; off < THREADS; off <<= 1) {
        int x = (t >= off) ? lbs[t - off] : 0;
        __syncthreads();
        lbs[t] += x;
        __syncthreads();
    }
    const int chunkBase = (blockIdx.x > 0) ? lbs[blockIdx.x - 1] : 0;

    // per-chunk scan of 1024 counters (4 per thread)  [R0-proven body]
    int base = blockIdx.x * 1024 + t * 4;
    int v[4]; int local = 0;
    #pragma unroll
    for (int k = 0; k < 4; ++k) {
        int i = base + k;
        v[k] = (i < N) ? cnt[i] : 0;
        local += v[k];
    }
    lds[t] = local; __syncthreads();
    for (int off = 1; off < THREADS; off <<= 1) {
        int x = (t >= off) ? lds[t - off] : 0;
        __syncthreads();
        lds[t] += x;
        __syncthreads();
    }
    int p = lds[t] - local + chunkBase;
    #pragma unroll
    for (int k = 0; k < 4; ++k) {
        int i = base + k;
        if (i < N) { rowptr[i] = p; cnt[i] = p; p += v[k]; }
    }
    if (blockIdx.x == 0 && t == 0) rowptr[N] = E;
}

// ---------------- scatter payload into CSR order (full 64B rows) ----------------
// payload row (16 floats, 64B): [s,u0,u1,u2 | Q00,Q01,Q02,Q11 | Q12,Q22,src,0 | 0,0,0,0]
// R0/R5 lesson: rows MUST be full 64B-aligned lines -- random 64B full-line writes pay
// no fill (WRITE_SIZE == payload bytes); 48B rows straddle sectors (R5: 227MB writes).
// Rank-based (ke) -> no atomics here (R3: atomic cursor added ~48MB RMW traffic).
// Plain stores so L2 merges the 4x16B into one line writeback (nt stores bypass: 2.4x).

__global__ __launch_bounds__(THREADS) void k_scatter5(const int* __restrict__ eidx,
                                                      const int* __restrict__ ke,    // null => atomic
                                                      const int* __restrict__ rowptr,
                                                      int* __restrict__ cursor,
                                                      const float* __restrict__ sh0,
                                                      const float* __restrict__ sh1,
                                                      const float* __restrict__ sh2,
                                                      float* __restrict__ pay,
                                                      int E) {
    int e = blockIdx.x * THREADS + threadIdx.x;
    if (e >= E) return;

    constexpr float IS10 = 0.31622776601683794f;
    constexpr float IS30 = 0.18257418583505536f;

    const int src = eidx[e];
    const int tgt = eidx[E + e];
    int pos;
    if (ke) pos = rowptr[tgt] + ke[e];
    else    pos = atomicAdd(&cursor[tgt], 1);

    // sequential input streams; nt so 58MB of sh doesn't evict hot data
    const float s  = __builtin_nontemporal_load(&sh0[e]);
    const float u0 = __builtin_nontemporal_load(&sh1[3*e+0]);
    const float u1 = __builtin_nontemporal_load(&sh1[3*e+1]);
    const float u2 = __builtin_nontemporal_load(&sh1[3*e+2]);
    const float q0 = __builtin_nontemporal_load(&sh2[5*e+0]);
    const float q1 = __builtin_nontemporal_load(&sh2[5*e+1]);
    const float q2 = __builtin_nontemporal_load(&sh2[5*e+2]);
    const float q3 = __builtin_nontemporal_load(&sh2[5*e+3]);
    const float q4 = __builtin_nontemporal_load(&sh2[5*e+4]);

    const float Q00 = -q2*IS30 - q4*IS10;
    const float Q01 =  q1*IS10;
    const float Q02 =  q0*IS10;
    const float Q11 =  2.0f*q2*IS30;
    const float Q12 =  q3*IS10;
    const float Q22 = -q2*IS30 + q4*IS10;

    float4* pr = (float4*)(pay + (size_t)pos * 16);
    pr[0] = make_float4(s, u0, u1, u2);
    pr[1] = make_float4(Q00, Q01, Q02, Q11);
    pr[2] = make_float4(Q12, Q22, __int_as_float(src), 0.f);
    pr[3] = make_float4(0.f, 0.f, 0.f, 0.f);   // full 64B line, one touch
}

// ---------------- aggregation: one WAVE per node, 64 lanes = 8 edges x 8 channels ----
// - zero divergence: loop bounds wave-uniform; tail masked by scaling node vec
//   (all 14 accumulator terms are linear in f0/x/y/z)
// - payload read with PLAIN loads: just written, 102MB < 256MB L3 -> should be
//   L3-resident (nt loads in R0-R3 bypassed allocation -> full HBM re-fetch)
// - per group-iteration: 8 payload rows = 512B contiguous; 8 node lines in flight
// - 1-deep pipeline: group g+1 payload + node vecs issued while computing g
// - end of node: reduce a[14] across jslot lanes via shfl_xor(8,16,32)

#define ACC_STRIDE 15   // 14 used +1 pad to break LDS bank conflicts

__global__ __launch_bounds__(THREADS) void k_agg8(const float* __restrict__ node,   // [N][32]
                                                  const int*   __restrict__ rowptr,
                                                  const float* __restrict__ pay,
                                                  const float* __restrict__ W,
                                                  float*       __restrict__ out,
                                                  int N) {
    __shared__ float sW[384];
    __shared__ float sAcc[32 * 8 * ACC_STRIDE];
    for (int t = threadIdx.x; t < 384; t += THREADS) sW[t] = W[t];
    __syncthreads();

    constexpr float IS3 = 0.57735026918962576f;
    constexpr float IS6 = 0.40824829046386302f;

    const int lane  = threadIdx.x & 63;
    const int wv    = threadIdx.x >> 6;    // wave 0..3
    const int i     = lane & 7;            // channel
    const int jslot = lane >> 3;           // edge slot 0..7

    for (int t = 0; t < 8; ++t) {
        const int n = blockIdx.x * 32 + wv * 8 + t;   // wave-uniform

        float a[14];
        #pragma unroll
        for (int k = 0; k < 14; ++k) a[k] = 0.f;

        if (n < N) {
            const int jbeg = rowptr[n];
            const int jend = rowptr[n + 1];

            if (jbeg < jend) {
                // prologue: group 0 payload + node vec
                int j  = jbeg + jslot;
                int jc = (j < jend) ? j : (jend - 1);
                float mcur = (j < jend) ? 1.f : 0.f;
                const v4f* p = (const v4f*)(pay + (size_t)jc * 16);
                v4f c0 = p[0], c1 = p[1], c2 = p[2];
                int src = __float_as_int(c2[2]);
                const float* nr = node + (size_t)src * 32;
                v4f nf;
                nf[0] = nr[i];
                nf[1] = nr[8 + 3*i + 0];
                nf[2] = nr[8 + 3*i + 1];
                nf[3] = nr[8 + 3*i + 2];

                for (int g0 = jbeg; g0 < jend; g0 += 8) {
                    const int gn = g0 + 8;
                    const bool more = gn < jend;   // wave-uniform
                    v4f d0, d1, d2; float mnext = 0.f;
                    if (more) {
                        int jn  = gn + jslot;
                        int jnc = (jn < jend) ? jn : (jend - 1);
                        mnext = (jn < jend) ? 1.f : 0.f;
                        const v4f* pn = (const v4f*)(pay + (size_t)jnc * 16);
                        d0 = pn[0]; d1 = pn[1]; d2 = pn[2];
                    }

                    const float f0 = nf[0] * mcur;
                    const float x  = nf[1] * mcur;
                    const float y  = nf[2] * mcur;
                    const float z  = nf[3] * mcur;
                    const float s   = c0[0], u0 = c0[1], u1 = c0[2], u2 = c0[3];
                    const float Q00 = c1[0], Q01 = c1[1], Q02 = c1[2], Q11 = c1[3];
                    const float Q12 = c2[0], Q22 = c2[1];

                    a[0]  += s * f0;
                    a[1]  += u0*x + u1*y + u2*z;
                    a[2]  += s * x;
                    a[3]  += s * y;
                    a[4]  += s * z;
                    a[5]  += f0 * u0;
                    a[6]  += f0 * u1;
                    a[7]  += f0 * u2;
                    a[8]  += u1*z - u2*y;
                    a[9]  += u2*x - u0*z;
                    a[10] += u0*y - u1*x;
                    a[11] += Q00*x + Q01*y + Q02*z;
                    a[12] += Q01*x + Q11*y + Q12*z;
                    a[13] += Q02*x + Q12*y + Q22*z;

                    if (more) {
                        int srcn = __float_as_int(d2[2]);
                        const float* nrn = node + (size_t)srcn * 32;
                        nf[0] = nrn[i];
                        nf[1] = nrn[8 + 3*i + 0];
                        nf[2] = nrn[8 + 3*i + 1];
                        nf[3] = nrn[8 + 3*i + 2];
                        c0 = d0; c1 = d1; c2 = d2; mcur = mnext;
                    }
                }
            }
        }

        // reduce across the 8 edge slots (lane bits 3..5); no divergence
        #pragma unroll
        for (int k = 0; k < 14; ++k) {
            float v = a[k];
            v += __shfl_xor(v, 8);
            v += __shfl_xor(v, 16);
            v += __shfl_xor(v, 32);
            a[k] = v;
        }

        if (n < N && jslot == 0) {
            #pragma unroll
            for (int k = 1; k < 8; ++k) a[k] *= IS3;
            #pragma unroll
            for (int k = 8; k < 11; ++k) a[k] *= IS6;
            float* myAcc = &sAcc[((wv * 8 + t) * 8 + i) * ACC_STRIDE];
            #pragma unroll
            for (int k = 0; k < 14; ++k) myAcc[k] = a[k];
        }
    }
    __syncthreads();

    // per-node postmix (channel-mixing weights), 8 threads per node
    {
        const int nodeSlot = threadIdx.x >> 3;
        const int o        = threadIdx.x & 7;
        const int n        = blockIdx.x * 32 + nodeSlot;
        if (n < N) {
            float o0 = 0.f, ox = 0.f, oy = 0.f, oz = 0.f;
            #pragma unroll
            for (int ii = 0; ii < 8; ++ii) {
                const float* A = &sAcc[(nodeSlot * 8 + ii) * ACC_STRIDE];
                const float w0 = sW[  0 + ii*8 + o];
                const float w1 = sW[ 64 + ii*8 + o];
                const float w2 = sW[128 + ii*8 + o];
                const float w3 = sW[192 + ii*8 + o];
                const float w4 = sW[256 + ii*8 + o];
                const float w5 = sW[320 + ii*8 + o];
                o0 += w0*A[0]  + w3*A[1];
                ox += w1*A[2]  + w2*A[5] + w4*A[8]  + w5*A[11];
                oy += w1*A[3]  + w2*A[6] + w4*A[9]  + w5*A[12];
                oz += w1*A[4]  + w2*A[7] + w4*A[10] + w5*A[13];
            }
            float* orow = out + (size_t)n * 32;
            orow[o]         = o0;
            orow[8 + 3*o+0] = ox;
            orow[8 + 3*o+1] = oy;
            orow[8 + 3*o+2] = oz;
        }
    }
}

// ---------------- fallback: atomic kernel (ws-free) ----------------

__global__ __launch_bounds__(THREADS) void msg_kernel_atomic(
    const float* __restrict__ node,
    const int*   __restrict__ eidx,
    const float* __restrict__ sh0,
    const float* __restrict__ sh1,
    const float* __restrict__ sh2,
    const float* __restrict__ W,
    float*       __restrict__ out,
    int E)
{
    __shared__ float sW[384];
    for (int t = threadIdx.x; t < 384; t += THREADS) sW[t] = W[t];
    __syncthreads();

    int e = blockIdx.x * THREADS + threadIdx.x;
    if (e >= E) return;

    constexpr float IS3  = 0.57735026918962576f;
    constexpr float IS6  = 0.40824829046386302f;
    constexpr float IS10 = 0.31622776601683794f;
    constexpr float IS30 = 0.18257418583505536f;

    const int src = eidx[e];
    const int tgt = eidx[E + e];

    const float s  = sh0[e];
    const float u0 = sh1[3*e+0], u1 = sh1[3*e+1], u2 = sh1[3*e+2];
    const float q0 = sh2[5*e+0], q1 = sh2[5*e+1], q2 = sh2[5*e+2],
                q3 = sh2[5*e+3], q4 = sh2[5*e+4];

    const float Q00 = -q2*IS30 - q4*IS10;
    const float Q01 =  q1*IS10;
    const float Q02 =  q0*IS10;
    const float Q11 =  2.0f*q2*IS30;
    const float Q12 =  q3*IS10;
    const float Q22 = -q2*IS30 + q4*IS10;

    float f[32];
    {
        const float4* nr = (const float4*)(node + (size_t)src * 32);
        #pragma unroll
        for (int i = 0; i < 8; ++i) {
            float4 v = nr[i];
            f[4*i+0]=v.x; f[4*i+1]=v.y; f[4*i+2]=v.z; f[4*i+3]=v.w;
        }
    }

    float msg[32];
    #pragma unroll
    for (int j = 0; j < 32; ++j) msg[j] = 0.0f;

    const float s13 = s * IS3;

    #pragma unroll
    for (int i = 0; i < 8; ++i) {
        const float f0i = f[i];
        const float x = f[8+3*i+0], y = f[8+3*i+1], z = f[8+3*i+2];
        const float c0  = s * f0i;
        const float c3  = IS3 * (u0*x + u1*y + u2*z);
        const float p2  = IS3 * f0i;
        const float c1x = s13*x, c1y = s13*y, c1z = s13*z;
        const float c2x = p2*u0, c2y = p2*u1, c2z = p2*u2;
        const float c4x = IS6*(u1*z - u2*y);
        const float c4y = IS6*(u2*x - u0*z);
        const float c4z = IS6*(u0*y - u1*x);
        const float c5x = Q00*x + Q01*y + Q02*z;
        const float c5y = Q01*x + Q11*y + Q12*z;
        const float c5z = Q02*x + Q12*y + Q22*z;

        float wr[6][8];
        #pragma unroll
        for (int c = 0; c < 6; ++c) {
            float4 aa = *(const float4*)&sW[c*64 + i*8 + 0];
            float4 bb = *(const float4*)&sW[c*64 + i*8 + 4];
            wr[c][0]=aa.x; wr[c][1]=aa.y; wr[c][2]=aa.z; wr[c][3]=aa.w;
            wr[c][4]=bb.x; wr[c][5]=bb.y; wr[c][6]=bb.z; wr[c][7]=bb.w;
        }

        #pragma unroll
        for (int o = 0; o < 8; ++o) {
            msg[o] += wr[0][o]*c0 + wr[3][o]*c3;
            msg[8+3*o+0] += wr[1][o]*c1x + wr[2][o]*c2x + wr[4][o]*c4x + wr[5][o]*c5x;
            msg[8+3*o+1] += wr[1][o]*c1y + wr[2][o]*c2y + wr[4][o]*c4y + wr[5][o]*c5y;
            msg[8+3*o+2] += wr[1][o]*c1z + wr[2][o]*c2z + wr[4][o]*c4z + wr[5][o]*c5z;
        }
    }

    float* orow = out + (size_t)tgt * 32;
    #pragma unroll
    for (int j = 0; j < 32; ++j) unsafeAtomicAdd(orow + j, msg[j]);
}

// ---------------- host ----------------

extern "C" void kernel_launch(void* const* d_in, const int* in_sizes, int n_in,
                              void* d_out, int out_size, void* d_ws, size_t ws_size,
                              hipStream_t stream) {
    const float* node = (const float*)d_in[0];
    const int*   eidx = (const int*)d_in[1];
    const float* sh0  = (const float*)d_in[2];
    const float* sh1  = (const float*)d_in[3];
    const float* sh2  = (const float*)d_in[4];
    const float* W    = (const float*)d_in[5];
    float* out = (float*)d_out;

    const int E = in_sizes[2];          // sh0 has E elements
    const int N = in_sizes[0] / 32;     // node_irreps is [N, 32]
    const int NB = (N + 1023) / 1024;   // scan chunks (1024 counters each)

    // ws layouts (words):
    //   tierA (ke):  cnt[N] | rowptr[N+1] | bsum[256] | ke[E] | (64B align) pay[16E]
    //   tierB:       cnt[N] | rowptr[N+1] | bsum[256] |       (64B align) pay[16E]
    size_t base_w = (size_t)N + (size_t)(N + 1) + 256;
    size_t intA_w = base_w + (size_t)E;
    size_t payA   = (intA_w + 15) & ~(size_t)15;
    size_t payB   = (base_w + 15) & ~(size_t)15;
    size_t needA  = (payA + (size_t)E * 16) * sizeof(float);
    size_t needB  = (payB + (size_t)E * 16) * sizeof(float);

    const int gridE = (E + THREADS - 1) / THREADS;

    // merged scan_final2 requires NB <= THREADS (=256) i.e. N <= 262144
    if (ws_size >= needB && NB <= THREADS) {
        const bool useKe = (ws_size >= needA);

        int* wsI    = (int*)d_ws;
        int* cnt    = wsI;
        int* rowptr = cnt + N;
        int* bsum   = rowptr + (N + 1);
        int* ke     = useKe ? (bsum + 256) : nullptr;
        float* pay  = (float*)d_ws + (useKe ? payA : payB);

        hipMemsetAsync(cnt, 0, (size_t)N * sizeof(int), stream);

        if (useKe)
            k_hist2<<<gridE, THREADS, 0, stream>>>(eidx + E, cnt, ke, E);
        else
            k_hist<<<gridE, THREADS, 0, stream>>>(eidx + E, cnt, E);

        k_scan_partial<<<NB, THREADS, 0, stream>>>(cnt, bsum, N);
        k_scan_final2<<<NB, THREADS, 0, stream>>>(cnt, bsum, rowptr, N, E, NB);

        k_scatter5<<<gridE, THREADS, 0, stream>>>(eidx, ke, rowptr, cnt,
                                                  sh0, sh1, sh2, pay, E);

        k_agg8<<<(N + 31) / 32, THREADS, 0, stream>>>(node, rowptr, pay, W, out, N);
    } else {
        hipMemsetAsync(d_out, 0, (size_t)out_size * sizeof(float), stream);
        msg_kernel_atomic<<<gridE, THREADS, 0, stream>>>(
            node, eidx, sh0, sh1, sh2, W, out, E);
    }
}

// Round 9
// 337.146 us; speedup vs baseline: 3.8332x; 1.0660x over previous
//
#include <hip/hip_runtime.h>

#define THREADS 256

typedef float v4f __attribute__((ext_vector_type(4)));
typedef int   v2i __attribute__((ext_vector_type(2)));

// ---------------- CSR build ----------------

// counts + per-target rank (atomic return value) -> colscat needs no atomics
__global__ __launch_bounds__(THREADS) void k_hist2(const int* __restrict__ tgt,
                                                   int* __restrict__ cnt,
                                                   int* __restrict__ ke, int E) {
    int e = blockIdx.x * THREADS + threadIdx.x;
    if (e < E) ke[e] = atomicAdd(&cnt[tgt[e]], 1);
}

// counts only (tier without ke array)
__global__ __launch_bounds__(THREADS) void k_hist(const int* __restrict__ tgt,
                                                  int* __restrict__ cnt, int E) {
    int e = blockIdx.x * THREADS + threadIdx.x;
    if (e < E) atomicAdd(&cnt[tgt[e]], 1);
}

// per-chunk partial sums (chunk = 1024 counters per block)  [R0-proven]
__global__ __launch_bounds__(THREADS) void k_scan_partial(const int* __restrict__ cnt,
                                                          int* __restrict__ bsum, int N) {
    __shared__ int lds[THREADS];
    int base = blockIdx.x * 1024 + threadIdx.x * 4;
    int s = 0;
    #pragma unroll
    for (int k = 0; k < 4; ++k) { int i = base + k; if (i < N) s += cnt[i]; }
    lds[threadIdx.x] = s; __syncthreads();
    for (int off = THREADS / 2; off > 0; off >>= 1) {
        if (threadIdx.x < off) lds[threadIdx.x] += lds[threadIdx.x + off];
        __syncthreads();
    }
    if (threadIdx.x == 0) bsum[blockIdx.x] = lds[0];
}

// finalize: every block redundantly scans bsum[NB<=256] in LDS, then per-chunk scan.
// Also writes cnt[i]=prefix (running cursor for the atomic-tier colscat).  [R8-proven]
__global__ __launch_bounds__(THREADS) void k_scan_final2(int* __restrict__ cnt,
                                                         const int* __restrict__ bsum,
                                                         int* __restrict__ rowptr,
                                                         int N, int E, int NB) {
    __shared__ int lbs[THREADS];
    __shared__ int lds[THREADS];
    const int t = threadIdx.x;

    lbs[t] = (t < NB) ? bsum[t] : 0;
    __syncthreads();
    for (int off = 1; off < THREADS; off <<= 1) {
        int x = (t >= off) ? lbs[t - off] : 0;
        __syncthreads();
        lbs[t] += x;
        __syncthreads();
    }
    const int chunkBase = (blockIdx.x > 0) ? lbs[blockIdx.x - 1] : 0;

    int base = blockIdx.x * 1024 + t * 4;
    int v[4]; int local = 0;
    #pragma unroll
    for (int k = 0; k < 4; ++k) {
        int i = base + k;
        v[k] = (i < N) ? cnt[i] : 0;
        local += v[k];
    }
    lds[t] = local; __syncthreads();
    for (int off = 1; off < THREADS; off <<= 1) {
        int x = (t >= off) ? lds[t - off] : 0;
        __syncthreads();
        lds[t] += x;
        __syncthreads();
    }
    int p = lds[t] - local + chunkBase;
    #pragma unroll
    for (int k = 0; k < 4; ++k) {
        int i = base + k;
        if (i < N) { rowptr[i] = p; cnt[i] = p; p += v[k]; }
    }
    if (blockIdx.x == 0 && t == 0) rowptr[N] = E;
}

// ---------------- scatter ONLY (e,src) pairs into CSR order (8B per edge) ----------
// Replaces the 64B payload scatter (101.7us, 112MB random writes, write-BW floor).
// 8B random writes land in a 12.8MB region < 32MB aggregate L2 -> lines accumulate
// all 16 pair-entries in L2 before writeback (R3 mechanism). All heavy per-edge data
// is gathered directly in k_agg9 (L3 absorbs line re-reads: R1 measured 3.45 TB/s).

__global__ __launch_bounds__(THREADS) void k_colscat2(const int* __restrict__ eidx,
                                                      const int* __restrict__ ke,   // null => atomic
                                                      const int* __restrict__ rowptr,
                                                      int* __restrict__ cursor,
                                                      int* __restrict__ col2,
                                                      int E) {
    int e = blockIdx.x * THREADS + threadIdx.x;
    if (e >= E) return;
    const int src = eidx[e];
    const int tgt = eidx[E + e];
    int pos;
    if (ke) pos = rowptr[tgt] + ke[e];
    else    pos = atomicAdd(&cursor[tgt], 1);
    v2i v; v[0] = e; v[1] = src;
    *(v2i*)(col2 + 2*(size_t)pos) = v;
}

// ---------------- aggregation: one WAVE per node, 64 lanes = 8 edges x 8 channels ----
// Wave-per-node skeleton (R8-proven: zero divergence, tail masked via node vec,
// shfl_xor(8,16,32) reduce) + DIRECT sh gathers by edge-id (R1 data path):
//   per edge: col2 pair 8B (stream, plain loads -> L2/L3 hit: just written)
//             sh0 4B + sh1 12B + sh2 20B random (L3 absorbs line re-reads)
//             node row: 16B at [i] and [8+3i] (128B line per edge across 8 lanes)
// Pipeline: pairs fetched 2 groups ahead, operands 1 group ahead (R2 discipline).
// Q computed in compute phase (VALU was 18% busy in agg8 -- headroom).

#define ACC_STRIDE 15   // 14 used +1 pad to break LDS bank conflicts

__global__ __launch_bounds__(THREADS) void k_agg9(const float* __restrict__ node,   // [N][32]
                                                  const int*   __restrict__ rowptr,
                                                  const int*   __restrict__ col2,   // (e,src) pairs
                                                  const float* __restrict__ sh0,
                                                  const float* __restrict__ sh1,
                                                  const float* __restrict__ sh2,
                                                  const float* __restrict__ W,
                                                  float*       __restrict__ out,
                                                  int N) {
    __shared__ float sW[384];
    __shared__ float sAcc[32 * 8 * ACC_STRIDE];
    for (int t = threadIdx.x; t < 384; t += THREADS) sW[t] = W[t];
    __syncthreads();

    constexpr float IS3  = 0.57735026918962576f;
    constexpr float IS6  = 0.40824829046386302f;
    constexpr float IS10 = 0.31622776601683794f;
    constexpr float IS30 = 0.18257418583505536f;

    const int lane  = threadIdx.x & 63;
    const int wv    = threadIdx.x >> 6;    // wave 0..3
    const int i     = lane & 7;            // channel
    const int jslot = lane >> 3;           // edge slot 0..7

    for (int t = 0; t < 8; ++t) {
        const int n = blockIdx.x * 32 + wv * 8 + t;   // wave-uniform

        float a[14];
        #pragma unroll
        for (int k = 0; k < 14; ++k) a[k] = 0.f;

        if (n < N) {
            const int jbeg = rowptr[n];
            const int jend = rowptr[n + 1];

            if (jbeg < jend) {
                const int jlast = jend - 1;

                // ---- prologue ----
                // group 0 pair + operands
                int j0  = jbeg + jslot;
                int jc0 = (j0 < jend) ? j0 : jlast;
                float mcur = (j0 < jend) ? 1.f : 0.f;
                v2i ec = *(const v2i*)(col2 + 2*(size_t)jc0);
                float s  = sh0[ec[0]];
                const float* up = sh1 + 3*(size_t)ec[0];
                float u0 = up[0], u1 = up[1], u2 = up[2];
                const float* qp = sh2 + 5*(size_t)ec[0];
                float q0 = qp[0], q1 = qp[1], q2 = qp[2], q3 = qp[3], q4 = qp[4];
                const float* nr = node + (size_t)ec[1] * 32;
                float f0 = nr[i];
                float x  = nr[8 + 3*i + 0];
                float y  = nr[8 + 3*i + 1];
                float z  = nr[8 + 3*i + 2];
                // group 1 pair
                int j1  = jbeg + 8 + jslot;
                int jc1 = (j1 < jend) ? j1 : jlast;
                v2i ecn = *(const v2i*)(col2 + 2*(size_t)jc1);

                for (int g0 = jbeg; g0 < jend; g0 += 8) {
                    const int gn = g0 + 8;
                    const bool more = gn < jend;   // wave-uniform
                    float ns = 0.f, nu0 = 0.f, nu1 = 0.f, nu2 = 0.f;
                    float nq0 = 0.f, nq1 = 0.f, nq2 = 0.f, nq3 = 0.f, nq4 = 0.f;
                    float nf0 = 0.f, nx = 0.f, ny = 0.f, nz = 0.f;
                    float mnext = 0.f;
                    v2i ec2 = ecn;
                    if (more) {
                        // operands for group g+1 (pair arrived a full iteration ago)
                        mnext = (gn + jslot < jend) ? 1.f : 0.f;
                        ns = sh0[ecn[0]];
                        const float* nup = sh1 + 3*(size_t)ecn[0];
                        nu0 = nup[0]; nu1 = nup[1]; nu2 = nup[2];
                        const float* nqp = sh2 + 5*(size_t)ecn[0];
                        nq0 = nqp[0]; nq1 = nqp[1]; nq2 = nqp[2]; nq3 = nqp[3]; nq4 = nqp[4];
                        const float* nrn = node + (size_t)ecn[1] * 32;
                        nf0 = nrn[i];
                        nx  = nrn[8 + 3*i + 0];
                        ny  = nrn[8 + 3*i + 1];
                        nz  = nrn[8 + 3*i + 2];
                        // pair for group g+2
                        int j2  = gn + 8 + jslot;
                        int jc2 = (j2 < jend) ? j2 : jlast;
                        ec2 = *(const v2i*)(col2 + 2*(size_t)jc2);
                    }

                    // ---- compute group g (operands loaded >= 1 iteration ago) ----
                    const float mf0 = f0 * mcur;
                    const float mx  = x  * mcur;
                    const float my  = y  * mcur;
                    const float mz  = z  * mcur;

                    const float Q00 = -q2*IS30 - q4*IS10;
                    const float Q01 =  q1*IS10;
                    const float Q02 =  q0*IS10;
                    const float Q11 =  2.0f*q2*IS30;
                    const float Q12 =  q3*IS10;
                    const float Q22 = -q2*IS30 + q4*IS10;

                    a[0]  += s * mf0;
                    a[1]  += u0*mx + u1*my + u2*mz;
                    a[2]  += s * mx;
                    a[3]  += s * my;
                    a[4]  += s * mz;
                    a[5]  += mf0 * u0;
                    a[6]  += mf0 * u1;
                    a[7]  += mf0 * u2;
                    a[8]  += u1*mz - u2*my;
                    a[9]  += u2*mx - u0*mz;
                    a[10] += u0*my - u1*mx;
                    a[11] += Q00*mx + Q01*my + Q02*mz;
                    a[12] += Q01*mx + Q11*my + Q12*mz;
                    a[13] += Q02*mx + Q12*my + Q22*mz;

                    // rotate pipeline
                    if (more) {
                        s = ns; u0 = nu0; u1 = nu1; u2 = nu2;
                        q0 = nq0; q1 = nq1; q2 = nq2; q3 = nq3; q4 = nq4;
                        f0 = nf0; x = nx; y = ny; z = nz;
                        ecn = ec2; mcur = mnext;
                    }
                }
            }
        }

        // reduce across the 8 edge slots (lane bits 3..5); no divergence
        #pragma unroll
        for (int k = 0; k < 14; ++k) {
            float v = a[k];
            v += __shfl_xor(v, 8);
            v += __shfl_xor(v, 16);
            v += __shfl_xor(v, 32);
            a[k] = v;
        }

        if (n < N && jslot == 0) {
            #pragma unroll
            for (int k = 1; k < 8; ++k) a[k] *= IS3;
            #pragma unroll
            for (int k = 8; k < 11; ++k) a[k] *= IS6;
            float* myAcc = &sAcc[((wv * 8 + t) * 8 + i) * ACC_STRIDE];
            #pragma unroll
            for (int k = 0; k < 14; ++k) myAcc[k] = a[k];
        }
    }
    __syncthreads();

    // per-node postmix (channel-mixing weights), 8 threads per node  [R8-proven]
    {
        const int nodeSlot = threadIdx.x >> 3;
        const int o        = threadIdx.x & 7;
        const int n        = blockIdx.x * 32 + nodeSlot;
        if (n < N) {
            float o0 = 0.f, ox = 0.f, oy = 0.f, oz = 0.f;
            #pragma unroll
            for (int ii = 0; ii < 8; ++ii) {
                const float* A = &sAcc[(nodeSlot * 8 + ii) * ACC_STRIDE];
                const float w0 = sW[  0 + ii*8 + o];
                const float w1 = sW[ 64 + ii*8 + o];
                const float w2 = sW[128 + ii*8 + o];
                const float w3 = sW[192 + ii*8 + o];
                const float w4 = sW[256 + ii*8 + o];
                const float w5 = sW[320 + ii*8 + o];
                o0 += w0*A[0]  + w3*A[1];
                ox += w1*A[2]  + w2*A[5] + w4*A[8]  + w5*A[11];
                oy += w1*A[3]  + w2*A[6] + w4*A[9]  + w5*A[12];
                oz += w1*A[4]  + w2*A[7] + w4*A[10] + w5*A[13];
            }
            float* orow = out + (size_t)n * 32;
            orow[o]         = o0;
            orow[8 + 3*o+0] = ox;
            orow[8 + 3*o+1] = oy;
            orow[8 + 3*o+2] = oz;
        }
    }
}

// ---------------- fallback: atomic kernel (ws-free) ----------------

__global__ __launch_bounds__(THREADS) void msg_kernel_atomic(
    const float* __restrict__ node,
    const int*   __restrict__ eidx,
    const float* __restrict__ sh0,
    const float* __restrict__ sh1,
    const float* __restrict__ sh2,
    const float* __restrict__ W,
    float*       __restrict__ out,
    int E)
{
    __shared__ float sW[384];
    for (int t = threadIdx.x; t < 384; t += THREADS) sW[t] = W[t];
    __syncthreads();

    int e = blockIdx.x * THREADS + threadIdx.x;
    if (e >= E) return;

    constexpr float IS3  = 0.57735026918962576f;
    constexpr float IS6  = 0.40824829046386302f;
    constexpr float IS10 = 0.31622776601683794f;
    constexpr float IS30 = 0.18257418583505536f;

    const int src = eidx[e];
    const int tgt = eidx[E + e];

    const float s  = sh0[e];
    const float u0 = sh1[3*e+0], u1 = sh1[3*e+1], u2 = sh1[3*e+2];
    const float q0 = sh2[5*e+0], q1 = sh2[5*e+1], q2 = sh2[5*e+2],
                q3 = sh2[5*e+3], q4 = sh2[5*e+4];

    const float Q00 = -q2*IS30 - q4*IS10;
    const float Q01 =  q1*IS10;
    const float Q02 =  q0*IS10;
    const float Q11 =  2.0f*q2*IS30;
    const float Q12 =  q3*IS10;
    const float Q22 = -q2*IS30 + q4*IS10;

    float f[32];
    {
        const float4* nr = (const float4*)(node + (size_t)src * 32);
        #pragma unroll
        for (int i = 0; i < 8; ++i) {
            float4 v = nr[i];
            f[4*i+0]=v.x; f[4*i+1]=v.y; f[4*i+2]=v.z; f[4*i+3]=v.w;
        }
    }

    float msg[32];
    #pragma unroll
    for (int j = 0; j < 32; ++j) msg[j] = 0.0f;

    const float s13 = s * IS3;

    #pragma unroll
    for (int i = 0; i < 8; ++i) {
        const float f0i = f[i];
        const float x = f[8+3*i+0], y = f[8+3*i+1], z = f[8+3*i+2];
        const float c0  = s * f0i;
        const float c3  = IS3 * (u0*x + u1*y + u2*z);
        const float p2  = IS3 * f0i;
        const float c1x = s13*x, c1y = s13*y, c1z = s13*z;
        const float c2x = p2*u0, c2y = p2*u1, c2z = p2*u2;
        const float c4x = IS6*(u1*z - u2*y);
        const float c4y = IS6*(u2*x - u0*z);
        const float c4z = IS6*(u0*y - u1*x);
        const float c5x = Q00*x + Q01*y + Q02*z;
        const float c5y = Q01*x + Q11*y + Q12*z;
        const float c5z = Q02*x + Q12*y + Q22*z;

        float wr[6][8];
        #pragma unroll
        for (int c = 0; c < 6; ++c) {
            float4 aa = *(const float4*)&sW[c*64 + i*8 + 0];
            float4 bb = *(const float4*)&sW[c*64 + i*8 + 4];
            wr[c][0]=aa.x; wr[c][1]=aa.y; wr[c][2]=aa.z; wr[c][3]=aa.w;
            wr[c][4]=bb.x; wr[c][5]=bb.y; wr[c][6]=bb.z; wr[c][7]=bb.w;
        }

        #pragma unroll
        for (int o = 0; o < 8; ++o) {
            msg[o] += wr[0][o]*c0 + wr[3][o]*c3;
            msg[8+3*o+0] += wr[1][o]*c1x + wr[2][o]*c2x + wr[4][o]*c4x + wr[5][o]*c5x;
            msg[8+3*o+1] += wr[1][o]*c1y + wr[2][o]*c2y + wr[4][o]*c4y + wr[5][o]*c5y;
            msg[8+3*o+2] += wr[1][o]*c1z + wr[2][o]*c2z + wr[4][o]*c4z + wr[5][o]*c5z;
        }
    }

    float* orow = out + (size_t)tgt * 32;
    #pragma unroll
    for (int j = 0; j < 32; ++j) unsafeAtomicAdd(orow + j, msg[j]);
}

// ---------------- host ----------------

extern "C" void kernel_launch(void* const* d_in, const int* in_sizes, int n_in,
                              void* d_out, int out_size, void* d_ws, size_t ws_size,
                              hipStream_t stream) {
    const float* node = (const float*)d_in[0];
    const int*   eidx = (const int*)d_in[1];
    const float* sh0  = (const float*)d_in[2];
    const float* sh1  = (const float*)d_in[3];
    const float* sh2  = (const float*)d_in[4];
    const float* W    = (const float*)d_in[5];
    float* out = (float*)d_out;

    const int E = in_sizes[2];          // sh0 has E elements
    const int N = in_sizes[0] / 32;     // node_irreps is [N, 32]
    const int NB = (N + 1023) / 1024;   // scan chunks (1024 counters each)

    // ws layouts (words):
    //   tierA (ke):  cnt[N] | rowptr[N+1] | bsum[256] | ke[E] | (align) col2[2E]
    //   tierB:       cnt[N] | rowptr[N+1] | bsum[256] |       (align) col2[2E]
    size_t base_w = (size_t)N + (size_t)(N + 1) + 256;
    size_t intA_w = base_w + (size_t)E;
    size_t colA   = (intA_w + 3) & ~(size_t)3;
    size_t colB   = (base_w + 3) & ~(size_t)3;
    size_t needA  = (colA + 2*(size_t)E) * sizeof(float);
    size_t needB  = (colB + 2*(size_t)E) * sizeof(float);

    const int gridE = (E + THREADS - 1) / THREADS;

    // merged scan_final2 requires NB <= THREADS (=256) i.e. N <= 262144
    if (ws_size >= needB && NB <= THREADS) {
        const bool useKe = (ws_size >= needA);

        int* wsI    = (int*)d_ws;
        int* cnt    = wsI;
        int* rowptr = cnt + N;
        int* bsum   = rowptr + (N + 1);
        int* ke     = useKe ? (bsum + 256) : nullptr;
        int* col2   = wsI + (useKe ? colA : colB);

        hipMemsetAsync(cnt, 0, (size_t)N * sizeof(int), stream);

        if (useKe)
            k_hist2<<<gridE, THREADS, 0, stream>>>(eidx + E, cnt, ke, E);
        else
            k_hist<<<gridE, THREADS, 0, stream>>>(eidx + E, cnt, E);

        k_scan_partial<<<NB, THREADS, 0, stream>>>(cnt, bsum, N);
        k_scan_final2<<<NB, THREADS, 0, stream>>>(cnt, bsum, rowptr, N, E, NB);

        k_colscat2<<<gridE, THREADS, 0, stream>>>(eidx, ke, rowptr, cnt, col2, E);

        k_agg9<<<(N + 31) / 32, THREADS, 0, stream>>>(node, rowptr, col2,
                                                      sh0, sh1, sh2, W, out, N);
    } else {
        hipMemsetAsync(d_out, 0, (size_t)out_size * sizeof(float), stream);
        msg_kernel_atomic<<<gridE, THREADS, 0, stream>>>(
            node, eidx, sh0, sh1, sh2, W, out, E);
    }
}